// Round 7
// baseline (456.666 us; speedup 1.0000x reference)
//
#include <hip/hip_runtime.h>
#include <stdint.h>
#include <stddef.h>

// Problem dims (fixed)
#define TT 2048
#define NH 16
#define HD 64
#define CM 1024            // d_model
#define QSCALE 0.1803368801f   // 0.125 * log2(e): softmax done in exp2 domain

typedef float f32x4  __attribute__((ext_vector_type(4)));
typedef short bf16x8 __attribute__((ext_vector_type(8)));
typedef unsigned u32x4v __attribute__((ext_vector_type(4)));

static __device__ __forceinline__ unsigned short f32_to_bf16(float f) {
    union { float f; unsigned u; } c; c.f = f;
    unsigned u = c.u;
    u += 0x7FFFu + ((u >> 16) & 1u);   // RNE
    return (unsigned short)(u >> 16);
}

// pack high-16s of two floats (truncation) into one u32: [hi|lo]
static __device__ __forceinline__ unsigned pack_bf16_trunc(float lo, float hi) {
    return __builtin_amdgcn_perm(__float_as_uint(hi), __float_as_uint(lo), 0x07060302u);
}

// async global->LDS, 16B per lane. LDS dest = wave-uniform base + lane*16.
static __device__ __forceinline__ void glds16(const unsigned short* g, unsigned short* l) {
    __builtin_amdgcn_global_load_lds(
        (const __attribute__((address_space(1))) unsigned int*)g,
        (__attribute__((address_space(3))) unsigned int*)l,
        16, 0, 0);
}

// HARDENED barrier (drain) — epilogues only.
static __device__ __forceinline__ void hard_barrier() {
    asm volatile("s_waitcnt vmcnt(0) lgkmcnt(0)" ::: "memory");
    __syncthreads();
}

// ---------------------------------------------------------------- casts
// float4-unit ranges: x 2097152 | qkv_w 786432 | out_w 262144
__global__ __launch_bounds__(256) void cast_all(
    const float* __restrict__ x, const float* __restrict__ w1,
    const float* __restrict__ w2,
    unsigned short* __restrict__ X16, unsigned short* __restrict__ W1o,
    unsigned short* __restrict__ W2o) {
    int i = blockIdx.x * blockDim.x + threadIdx.x;
    const float* src; unsigned short* dst; int j;
    if (i < 2097152)      { src = x;  dst = X16; j = i; }
    else if (i < 2883584) { src = w1; dst = W1o; j = i - 2097152; }
    else                  { src = w2; dst = W2o; j = i - 2883584; }
    float4 v = ((const float4*)src)[j];
    ushort4 o;
    o.x = f32_to_bf16(v.x); o.y = f32_to_bf16(v.y);
    o.z = f32_to_bf16(v.z); o.w = f32_to_bf16(v.w);
    ((ushort4*)dst)[j] = o;
}

// ---------------------------------------------------------------- GEMM core
// 256x128 tile, 4 waves of 128x64. BK=32, dbuf 48KB LDS, counted-vmcnt
// pipeline (vmcnt(6) in-loop, never drains). XOR chunk swizzle as verified.
// SWAP=true computes C^T = mfma(B,A): D col (l15) = m index, D rows = n.
template<bool SWAP>
__device__ __forceinline__ void gemm256_core(
    const unsigned short* __restrict__ A,
    const unsigned short* __restrict__ Bm,
    int m0, int n0,
    unsigned short* lds,
    f32x4 acc[8][4])
{
    const int tid  = threadIdx.x;
    const int lane = tid & 63;
    const int w    = tid >> 6;
    const int l15  = lane & 15;
    const int quad = lane >> 4;
    const int wm   = (w >> 1) * 128;
    const int wn   = (w & 1) * 64;
    const int ro   = (quad ^ (l15 & 3)) * 8;   // read-side swizzle

    const int rr = tid >> 2;
    const int ch = (tid & 3) ^ (rr & 3);
    const unsigned short* gA = A  + (size_t)(m0 + rr) * CM + ch * 8;
    const unsigned short* gB = Bm + (size_t)(n0 + rr) * CM + ch * 8;
    const int wb = (tid & ~63) * 8;            // wave-uniform dest base

    unsigned short* ldsA = lds;                // 2 x 8192 shorts
    unsigned short* ldsB = lds + 16384;        // 2 x 4096 shorts

#define STAGE6(bb)                                                    \
    {                                                                 \
        unsigned short* dA = ldsA + (bb) * 8192 + wb;                 \
        unsigned short* dB = ldsB + (bb) * 4096 + wb;                 \
        glds16(gA,            dA);                                    \
        glds16(gA +  64 * CM, dA + 2048);                             \
        glds16(gA + 128 * CM, dA + 4096);                             \
        glds16(gA + 192 * CM, dA + 6144);                             \
        glds16(gB,            dB);                                    \
        glds16(gB +  64 * CM, dB + 2048);                             \
        gA += 32; gB += 32;                                           \
    }

    STAGE6(0);
    STAGE6(1);

    for (int t = 0; t < 32; ++t) {
        if (t > 0) {
            asm volatile("s_waitcnt lgkmcnt(0)" ::: "memory");
            __builtin_amdgcn_s_barrier();
            asm volatile("" ::: "memory");
            if (t + 1 < 32) STAGE6((t + 1) & 1);
        }
        if (t + 1 < 32) asm volatile("s_waitcnt vmcnt(6)" ::: "memory");
        else            asm volatile("s_waitcnt vmcnt(0)" ::: "memory");
        __builtin_amdgcn_s_barrier();
        asm volatile("" ::: "memory");

        const unsigned short* tA = ldsA + (t & 1) * 8192;
        const unsigned short* tB = ldsB + (t & 1) * 4096;

        bf16x8 bfr[4];
        #pragma unroll
        for (int ni = 0; ni < 4; ++ni)
            bfr[ni] = *(const bf16x8*)(tB + (wn + ni * 16 + l15) * 32 + ro);
        bf16x8 af[8];
        #pragma unroll
        for (int mi = 0; mi < 8; ++mi)
            af[mi] = *(const bf16x8*)(tA + (wm + mi * 16 + l15) * 32 + ro);

        #pragma unroll
        for (int mi = 0; mi < 8; ++mi)
            #pragma unroll
            for (int ni = 0; ni < 4; ++ni)
                acc[mi][ni] = SWAP
                    ? __builtin_amdgcn_mfma_f32_16x16x32_bf16(bfr[ni], af[mi], acc[mi][ni], 0, 0, 0)
                    : __builtin_amdgcn_mfma_f32_16x16x32_bf16(af[mi], bfr[ni], acc[mi][ni], 0, 0, 0);
    }
#undef STAGE6
}

// ---------------------------------------------------------------- QKV GEMM
__global__ __launch_bounds__(256, 2) void gemm_qkv(
    const unsigned short* __restrict__ X,
    const unsigned short* __restrict__ W,
    const float* __restrict__ bias,
    unsigned short* __restrict__ Qb,
    unsigned short* __restrict__ Kb,
    unsigned short* __restrict__ Vt)
{
    __shared__ __align__(16) unsigned short lds[24576];   // 48KB
    const int m0 = blockIdx.y * 256;
    const int n0 = blockIdx.x * 128;

    f32x4 acc[8][4];
    f32x4 z = {0.f, 0.f, 0.f, 0.f};
    #pragma unroll
    for (int mi = 0; mi < 8; ++mi)
        #pragma unroll
        for (int ni = 0; ni < 4; ++ni) acc[mi][ni] = z;

    const int region = n0 >> 10;            // 0=Q 1=K 2=V
    if (region < 2) gemm256_core<true >(X, W, m0, n0, lds, acc);
    else            gemm256_core<false>(X, W, m0, n0, lds, acc);

    const int tid  = threadIdx.x;
    const int lane = tid & 63;
    const int w    = tid >> 6;
    const int wm   = (w >> 1) * 128;
    const int wn   = (w & 1) * 64;
    const int l15  = lane & 15;
    const int quad = lane >> 4;
    const int b_idx = m0 >> 11;
    const int t0 = m0 & 2047;

    if (region == 2) {
        // V: transpose through LDS, store coalesced rows of V^T[d][t]
        hard_barrier();
        #pragma unroll
        for (int hn = 0; hn < 2; ++hn) {
            if ((w & 1) == hn) {
                #pragma unroll
                for (int ni = 0; ni < 4; ++ni) {
                    const int nloc = ni * 16 + l15;
                    const float bv = bias[n0 + hn * 64 + nloc];
                    #pragma unroll
                    for (int mi = 0; mi < 8; ++mi) {
                        uint2 pk;
                        pk.x = (unsigned)f32_to_bf16(acc[mi][ni][0] + bv) |
                               ((unsigned)f32_to_bf16(acc[mi][ni][1] + bv) << 16);
                        pk.y = (unsigned)f32_to_bf16(acc[mi][ni][2] + bv) |
                               ((unsigned)f32_to_bf16(acc[mi][ni][3] + bv) << 16);
                        *(uint2*)(lds + nloc * 264 + wm + mi * 16 + quad * 4) = pk;
                    }
                }
            }
            hard_barrier();
            {
                const int row = tid >> 2, seg = tid & 3;
                const int o   = n0 + hn * 64 + row;
                const int oin = o & 1023;
                const int hh  = oin >> 6, d = oin & 63;
                unsigned short* dst = Vt + ((size_t)((b_idx << 4) + hh) * HD + d) * TT
                                        + t0 + seg * 64;
                const unsigned short* src = lds + row * 264 + seg * 64;
                #pragma unroll
                for (int u = 0; u < 8; ++u)
                    *(uint4*)(dst + u * 8) = *(const uint4*)(src + u * 8);
            }
            hard_barrier();
        }
        return;
    }

    // Q/K swapped epilogue: col(l15) = t, rows = o; 8B stores of 4 d's
    unsigned short* dst0 = region ? Kb : Qb;
    const float scl = region ? 1.0f : QSCALE;
    #pragma unroll
    for (int mi = 0; mi < 8; ++mi) {
        const int gm = m0 + wm + mi * 16 + l15;
        const int t  = gm & 2047;
        #pragma unroll
        for (int ni = 0; ni < 4; ++ni) {
            const int o  = n0 + wn + ni * 16 + quad * 4;
            const float4 bv = *(const float4*)(bias + o);
            const int oin = o & 1023;
            const int hh = oin >> 6, d = oin & 63;
            const int bh = (b_idx << 4) + hh;
            const float v0 = (acc[mi][ni][0] + bv.x) * scl;
            const float v1 = (acc[mi][ni][1] + bv.y) * scl;
            const float v2 = (acc[mi][ni][2] + bv.z) * scl;
            const float v3 = (acc[mi][ni][3] + bv.w) * scl;
            uint2 pk;
            pk.x = (unsigned)f32_to_bf16(v0) | ((unsigned)f32_to_bf16(v1) << 16);
            pk.y = (unsigned)f32_to_bf16(v2) | ((unsigned)f32_to_bf16(v3) << 16);
            *(uint2*)(dst0 + (((size_t)(bh * TT + t)) << 6) + d) = pk;
        }
    }
}

// ---------------------------------------------------------------- attention
// R6 post-mortem: the in-register P exchange was CORRECT but the union used
// to assemble bf16x8 from 4 u32s blocked SROA -> alloca -> scratch: 620MB/
// dispatch of scratch traffic (WRITE 634MB, VGPR fell 108->84). R7: same
// structure, union replaced by ext-vector named-field construction +
// __builtin_bit_cast (no alloca possible). Everything else unchanged:
//  - P never touches LDS (16 ds_bpermute + 8 selects per f-half).
//  - LDS 32KB (K/V dbuf), launch_bounds(256,3).
//  - counted vmcnt(4) staging, never drains in-loop.
//  - XCD grouping: all 16 qt of a bh on one XCD.
__global__ __launch_bounds__(256, 3) void attn_kernel(
    const unsigned short* __restrict__ Qb,
    const unsigned short* __restrict__ Kb,
    const unsigned short* __restrict__ Vt,
    unsigned short* __restrict__ CTX)
{
    __shared__ __align__(16) unsigned short Kl[2][4096];   // 16KB
    __shared__ __align__(16) unsigned short Vl[2][4096];   // 16KB

    const int id  = blockIdx.x;
    const int xcd = id & 7, j = id >> 3;
    const int bh  = (xcd << 3) | (j & 7);    // same bh -> same XCD (L2 reuse)
    const int qt  = 15 - (j >> 3);           // heavy-first within XCD
    const int b  = bh >> 4, h = bh & 15;
    const int tid  = threadIdx.x;
    const int lane = tid & 63;
    const int w    = tid >> 6;
    const int l15  = lane & 15;
    const int quad = lane >> 4;
    const int sw   = l15 & 7;              // read-side swizzle key
    const int bhh  = b * NH + h;

    const unsigned short* Kbase = Kb + (size_t)bhh * TT * HD;  // [t][d]
    const unsigned short* Vbase = Vt + (size_t)bhh * HD * TT;  // [d][t]
    const f32x4 z = {0.f, 0.f, 0.f, 0.f};

    const int c1 = tid, c2 = tid + 256;
    const int row1 = c1 >> 3, col1 = ((c1 & 7) ^ (row1 & 7)) * 8;
    const int row2 = c2 >> 3, col2 = ((c2 & 7) ^ (row2 & 7)) * 8;
    unsigned short* dK1 = &Kl[0][(c1 & ~63) * 8];
    unsigned short* dK2 = &Kl[0][(c2 & ~63) * 8];
    unsigned short* dV1 = &Vl[0][(c1 & ~63) * 8];
    unsigned short* dV2 = &Vl[0][(c2 & ~63) * 8];

    const int len = 2 * qt + 2;            // tiles 0..len-1
    const int qb0 = qt * 128;

    const unsigned short* kp1 = Kbase + (size_t)row1 * HD + col1;
    const unsigned short* kp2 = Kbase + (size_t)row2 * HD + col2;
    const unsigned short* vp1 = Vbase + (size_t)row1 * TT + col1;
    const unsigned short* vp2 = Vbase + (size_t)row2 * TT + col2;

    bf16x8 qf[2][2];
    #pragma unroll
    for (int f = 0; f < 2; ++f) {
        const unsigned short* qr =
            Qb + (size_t)(bhh * TT + qb0 + f * 64 + w * 16 + l15) * HD + quad * 8;
        qf[f][0] = *(const bf16x8*)(qr);
        qf[f][1] = *(const bf16x8*)(qr + 32);
    }

    f32x4 o_acc[2][4];
    #pragma unroll
    for (int f = 0; f < 2; ++f)
        #pragma unroll
        for (int di = 0; di < 4; ++di) o_acc[f][di] = z;
    float lrun[2] = {0.f, 0.f};

    // bpermute source byte-addresses (loop-invariant)
    const int srcA = (l15 + 32 * (quad & 1)) * 4;
    const int srcB = srcA + 64;            // +16 lanes
    const bool selhi = (quad >> 1) != 0;

#define STAGE_KV(bufidx)                                               \
    {                                                                  \
        const int nx = (bufidx) * 4096;                                \
        glds16(kp1, dK1 + nx); glds16(kp2, dK2 + nx);                  \
        glds16(vp1, dV1 + nx); glds16(vp2, dV2 + nx);                  \
        kp1 += 64 * HD; kp2 += 64 * HD; vp1 += 64; vp2 += 64;          \
    }
    STAGE_KV(0);
    if (len > 1) STAGE_KV(1);

    for (int i = 0; i < len; ++i) {
        const int cur = i & 1;
        if (i > 0) {
            asm volatile("s_waitcnt lgkmcnt(0)" ::: "memory"); // reads of retiring buf done
            __builtin_amdgcn_s_barrier();                      // all waves -> WAR safe
            asm volatile("" ::: "memory");
            if (i + 1 < len) STAGE_KV((i + 1) & 1);
        }
        if (i + 1 < len) asm volatile("s_waitcnt vmcnt(4)" ::: "memory"); // tile i landed
        else             asm volatile("s_waitcnt vmcnt(0)" ::: "memory");
        __builtin_amdgcn_s_barrier();
        asm volatile("" ::: "memory");

        const unsigned short* Kt    = &Kl[0][0] + cur * 4096;
        const unsigned short* Vtile = &Vl[0][0] + cur * 4096;
        const bool f0act = (i < len - 1);

        f32x4 s0[4], s1[4];
        #pragma unroll
        for (int ni = 0; ni < 4; ++ni) {
            const unsigned short* kr = Kt + (ni * 16 + l15) * 64;
            bf16x8 kf0 = *(const bf16x8*)(kr + ((quad ^ sw) * 8));
            bf16x8 kf1 = *(const bf16x8*)(kr + (((quad + 4) ^ sw) * 8));
            if (f0act) {
                f32x4 a = __builtin_amdgcn_mfma_f32_16x16x32_bf16(kf0, qf[0][0], z, 0, 0, 0);
                s0[ni] = __builtin_amdgcn_mfma_f32_16x16x32_bf16(kf1, qf[0][1], a, 0, 0, 0);
            }
            f32x4 a1 = __builtin_amdgcn_mfma_f32_16x16x32_bf16(kf0, qf[1][0], z, 0, 0, 0);
            s1[ni] = __builtin_amdgcn_mfma_f32_16x16x32_bf16(kf1, qf[1][1], a1, 0, 0, 0);
        }

        const int qloc = w * 16 + l15;
        if (f0act && i == len - 2) {
            #pragma unroll
            for (int ni = 0; ni < 4; ++ni)
                #pragma unroll
                for (int r = 0; r < 4; ++r)
                    if (ni * 16 + quad * 4 + r > qloc) s0[ni][r] = -1e30f;
        }
        if (i == len - 1) {
            #pragma unroll
            for (int ni = 0; ni < 4; ++ni)
                #pragma unroll
                for (int r = 0; r < 4; ++r)
                    if (ni * 16 + quad * 4 + r > qloc) s1[ni][r] = -1e30f;
        }

        // softmax (exp2, tree sum) + in-register P->B-fragment exchange.
        // Vector assembled via named fields + bit_cast (NO union/alloca).
        bf16x8 pf0[2], pf1[2];
        #define SOFTMAX_X(S, PF, F)                                          \
        {                                                                    \
            float tni[4];                                                    \
            unsigned pkA[4], pkB[4];                                         \
            _Pragma("unroll")                                                \
            for (int ni = 0; ni < 4; ++ni) {                                 \
                float p0 = __builtin_amdgcn_exp2f(S[ni][0]);                 \
                float p1 = __builtin_amdgcn_exp2f(S[ni][1]);                 \
                float p2 = __builtin_amdgcn_exp2f(S[ni][2]);                 \
                float p3 = __builtin_amdgcn_exp2f(S[ni][3]);                 \
                tni[ni] = (p0 + p1) + (p2 + p3);                             \
                pkA[ni] = pack_bf16_trunc(p0, p1);                           \
                pkB[ni] = pack_bf16_trunc(p2, p3);                           \
            }                                                                \
            lrun[F] += (tni[0] + tni[1]) + (tni[2] + tni[3]);                \
            _Pragma("unroll")                                                \
            for (int c = 0; c < 2; ++c) {                                    \
                const int n0i = 2 * c, n1i = 2 * c + 1;                      \
                unsigned q00 = __builtin_amdgcn_ds_bpermute(srcA, pkA[n0i]); \
                unsigned q01 = __builtin_amdgcn_ds_bpermute(srcA, pkB[n0i]); \
                unsigned q02 = __builtin_amdgcn_ds_bpermute(srcB, pkA[n0i]); \
                unsigned q03 = __builtin_amdgcn_ds_bpermute(srcB, pkB[n0i]); \
                unsigned q10 = __builtin_amdgcn_ds_bpermute(srcA, pkA[n1i]); \
                unsigned q11 = __builtin_amdgcn_ds_bpermute(srcA, pkB[n1i]); \
                unsigned q12 = __builtin_amdgcn_ds_bpermute(srcB, pkA[n1i]); \
                unsigned q13 = __builtin_amdgcn_ds_bpermute(srcB, pkB[n1i]); \
                u32x4v t;                                                    \
                t.x = selhi ? q10 : q00;                                     \
                t.y = selhi ? q11 : q01;                                     \
                t.z = selhi ? q12 : q02;                                     \
                t.w = selhi ? q13 : q03;                                     \
                PF[c] = __builtin_bit_cast(bf16x8, t);                       \
            }                                                                \
        }

        SOFTMAX_X(s1, pf1, 1);
        if (f0act) SOFTMAX_X(s0, pf0, 0);
        #undef SOFTMAX_X

        // PV: one V read serves both f halves.
        #pragma unroll
        for (int c = 0; c < 2; ++c) {
            #pragma unroll
            for (int di = 0; di < 4; ++di) {
                const unsigned short* vr = Vtile + (di * 16 + l15) * 64
                                         + (((c * 4 + quad) ^ sw) * 8);
                bf16x8 vf = *(const bf16x8*)(vr);
                o_acc[1][di] = __builtin_amdgcn_mfma_f32_16x16x32_bf16(vf, pf1[c], o_acc[1][di], 0, 0, 0);
                if (f0act)
                    o_acc[0][di] = __builtin_amdgcn_mfma_f32_16x16x32_bf16(vf, pf0[c], o_acc[0][di], 0, 0, 0);
            }
        }
    }
#undef STAGE_KV

    #pragma unroll
    for (int f = 0; f < 2; ++f) {
        float lt = lrun[f];
        lt += __shfl_xor(lt, 16);
        lt += __shfl_xor(lt, 32);
        const float inv = 1.0f / lt;
        unsigned short* crow =
            CTX + (size_t)(b * TT + qb0 + f * 64 + w * 16 + l15) * CM + h * HD;
        #pragma unroll
        for (int di = 0; di < 4; ++di) {
            uint2 pk;
            pk.x = (unsigned)f32_to_bf16(o_acc[f][di][0] * inv) |
                   ((unsigned)f32_to_bf16(o_acc[f][di][1] * inv) << 16);
            pk.y = (unsigned)f32_to_bf16(o_acc[f][di][2] * inv) |
                   ((unsigned)f32_to_bf16(o_acc[f][di][3] * inv) << 16);
            *(uint2*)(crow + di * 16 + quad * 4) = pk;
        }
    }
}

// ---------------------------------------------------------------- out proj
__global__ __launch_bounds__(256, 2) void gemm_out(
    const unsigned short* __restrict__ CTX,
    const unsigned short* __restrict__ W,
    const float* __restrict__ bias,
    float* __restrict__ out)
{
    __shared__ __align__(16) unsigned short lds[24576];
    const int m0 = blockIdx.y * 256;
    const int n0 = blockIdx.x * 128;

    f32x4 acc[8][4];
    f32x4 z = {0.f, 0.f, 0.f, 0.f};
    #pragma unroll
    for (int mi = 0; mi < 8; ++mi)
        #pragma unroll
        for (int ni = 0; ni < 4; ++ni) acc[mi][ni] = z;

    gemm256_core<true>(CTX, W, m0, n0, lds, acc);

    const int tid  = threadIdx.x;
    const int lane = tid & 63;
    const int w    = tid >> 6;
    const int wm   = (w >> 1) * 128;
    const int wn   = (w & 1) * 64;
    const int l15  = lane & 15;
    const int quad = lane >> 4;

    #pragma unroll
    for (int mi = 0; mi < 8; ++mi) {
        const int gm = m0 + wm + mi * 16 + l15;
        float* orow = out + (size_t)gm * CM;
        #pragma unroll
        for (int ni = 0; ni < 4; ++ni) {
            const int o = n0 + wn + ni * 16 + quad * 4;
            const float4 bv = *(const float4*)(bias + o);
            float4 v;
            v.x = acc[mi][ni][0] + bv.x;
            v.y = acc[mi][ni][1] + bv.y;
            v.z = acc[mi][ni][2] + bv.z;
            v.w = acc[mi][ni][3] + bv.w;
            *(float4*)(orow + o) = v;
        }
    }
}

// ---------------------------------------------------------------- launch
extern "C" void kernel_launch(void* const* d_in, const int* in_sizes, int n_in,
                              void* d_out, int out_size, void* d_ws, size_t ws_size,
                              hipStream_t stream) {
    const float* x     = (const float*)d_in[0];
    const float* qkv_w = (const float*)d_in[1];
    const float* qkv_b = (const float*)d_in[2];
    const float* out_w = (const float*)d_in[3];
    const float* out_b = (const float*)d_in[4];
    float* out = (float*)d_out;

    char* ws = (char*)d_ws;
    unsigned short* X16 = (unsigned short*)(ws + 0);         // 16 MB
    unsigned short* W1  = (unsigned short*)(ws + 16777216);  // 6 MB
    unsigned short* W2  = (unsigned short*)(ws + 23068672);  // 2 MB
    unsigned short* Qb  = (unsigned short*)(ws + 25165824);  // 16 MB
    unsigned short* Kb  = (unsigned short*)(ws + 41943040);  // 16 MB
    unsigned short* Vt  = (unsigned short*)(ws + 58720256);  // 16 MB
    unsigned short* CTX = (unsigned short*)(ws + 75497472);  // 16 MB  (~92 MB)

    cast_all<<<12288, 256, 0, stream>>>(x, qkv_w, out_w, X16, W1, W2);

    gemm_qkv<<<dim3(24, 32), 256, 0, stream>>>(X16, W1, qkv_b, Qb, Kb, Vt);
    attn_kernel<<<1024, 256, 0, stream>>>(Qb, Kb, Vt, CTX);
    gemm_out<<<dim3(8, 32), 256, 0, stream>>>(CTX, W2, out_b, out);
}

// Round 8
// 254.430 us; speedup vs baseline: 1.7949x; 1.7949x over previous
//
#include <hip/hip_runtime.h>
#include <stdint.h>
#include <stddef.h>

// Problem dims (fixed)
#define TT 2048
#define NH 16
#define HD 64
#define CM 1024            // d_model
#define QSCALE 0.1803368801f   // 0.125 * log2(e): softmax done in exp2 domain
#define PPAD 72

typedef float f32x4  __attribute__((ext_vector_type(4)));
typedef short bf16x8 __attribute__((ext_vector_type(8)));

static __device__ __forceinline__ unsigned short f32_to_bf16(float f) {
    union { float f; unsigned u; } c; c.f = f;
    unsigned u = c.u;
    u += 0x7FFFu + ((u >> 16) & 1u);   // RNE
    return (unsigned short)(u >> 16);
}

// pack high-16s of two floats (truncation) into one u32: [hi|lo]
static __device__ __forceinline__ unsigned pack_bf16_trunc(float lo, float hi) {
    return __builtin_amdgcn_perm(__float_as_uint(hi), __float_as_uint(lo), 0x07060302u);
}

// async global->LDS, 16B per lane. LDS dest = wave-uniform base + lane*16.
static __device__ __forceinline__ void glds16(const unsigned short* g, unsigned short* l) {
    __builtin_amdgcn_global_load_lds(
        (const __attribute__((address_space(1))) unsigned int*)g,
        (__attribute__((address_space(3))) unsigned int*)l,
        16, 0, 0);
}

// HARDENED barrier (drain) — epilogues only.
static __device__ __forceinline__ void hard_barrier() {
    asm volatile("s_waitcnt vmcnt(0) lgkmcnt(0)" ::: "memory");
    __syncthreads();
}

// ---------------------------------------------------------------- casts
// float4-unit ranges: x 2097152 | qkv_w 786432 | out_w 262144
__global__ __launch_bounds__(256) void cast_all(
    const float* __restrict__ x, const float* __restrict__ w1,
    const float* __restrict__ w2,
    unsigned short* __restrict__ X16, unsigned short* __restrict__ W1o,
    unsigned short* __restrict__ W2o) {
    int i = blockIdx.x * blockDim.x + threadIdx.x;
    const float* src; unsigned short* dst; int j;
    if (i < 2097152)      { src = x;  dst = X16; j = i; }
    else if (i < 2883584) { src = w1; dst = W1o; j = i - 2097152; }
    else                  { src = w2; dst = W2o; j = i - 2883584; }
    float4 v = ((const float4*)src)[j];
    ushort4 o;
    o.x = f32_to_bf16(v.x); o.y = f32_to_bf16(v.y);
    o.z = f32_to_bf16(v.z); o.w = f32_to_bf16(v.w);
    ((ushort4*)dst)[j] = o;
}

// ---------------------------------------------------------------- GEMM core
// 256x128 tile, 4 waves of 128x64. BK=32, dbuf 48KB LDS, counted-vmcnt
// pipeline (vmcnt(6) in-loop, never drains). XOR chunk swizzle as verified.
// SWAP=true computes C^T = mfma(B,A): D col (l15) = m index, D rows = n.
template<bool SWAP>
__device__ __forceinline__ void gemm256_core(
    const unsigned short* __restrict__ A,
    const unsigned short* __restrict__ Bm,
    int m0, int n0,
    unsigned short* lds,
    f32x4 acc[8][4])
{
    const int tid  = threadIdx.x;
    const int lane = tid & 63;
    const int w    = tid >> 6;
    const int l15  = lane & 15;
    const int quad = lane >> 4;
    const int wm   = (w >> 1) * 128;
    const int wn   = (w & 1) * 64;
    const int ro   = (quad ^ (l15 & 3)) * 8;   // read-side swizzle

    const int rr = tid >> 2;
    const int ch = (tid & 3) ^ (rr & 3);
    const unsigned short* gA = A  + (size_t)(m0 + rr) * CM + ch * 8;
    const unsigned short* gB = Bm + (size_t)(n0 + rr) * CM + ch * 8;
    const int wb = (tid & ~63) * 8;            // wave-uniform dest base

    unsigned short* ldsA = lds;                // 2 x 8192 shorts
    unsigned short* ldsB = lds + 16384;        // 2 x 4096 shorts

#define STAGE6(bb)                                                    \
    {                                                                 \
        unsigned short* dA = ldsA + (bb) * 8192 + wb;                 \
        unsigned short* dB = ldsB + (bb) * 4096 + wb;                 \
        glds16(gA,            dA);                                    \
        glds16(gA +  64 * CM, dA + 2048);                             \
        glds16(gA + 128 * CM, dA + 4096);                             \
        glds16(gA + 192 * CM, dA + 6144);                             \
        glds16(gB,            dB);                                    \
        glds16(gB +  64 * CM, dB + 2048);                             \
        gA += 32; gB += 32;                                           \
    }

    STAGE6(0);
    STAGE6(1);

    for (int t = 0; t < 32; ++t) {
        if (t > 0) {
            asm volatile("s_waitcnt lgkmcnt(0)" ::: "memory");
            __builtin_amdgcn_s_barrier();
            asm volatile("" ::: "memory");
            if (t + 1 < 32) STAGE6((t + 1) & 1);
        }
        if (t + 1 < 32) asm volatile("s_waitcnt vmcnt(6)" ::: "memory");
        else            asm volatile("s_waitcnt vmcnt(0)" ::: "memory");
        __builtin_amdgcn_s_barrier();
        asm volatile("" ::: "memory");

        const unsigned short* tA = ldsA + (t & 1) * 8192;
        const unsigned short* tB = ldsB + (t & 1) * 4096;

        bf16x8 bfr[4];
        #pragma unroll
        for (int ni = 0; ni < 4; ++ni)
            bfr[ni] = *(const bf16x8*)(tB + (wn + ni * 16 + l15) * 32 + ro);
        bf16x8 af[8];
        #pragma unroll
        for (int mi = 0; mi < 8; ++mi)
            af[mi] = *(const bf16x8*)(tA + (wm + mi * 16 + l15) * 32 + ro);

        #pragma unroll
        for (int mi = 0; mi < 8; ++mi)
            #pragma unroll
            for (int ni = 0; ni < 4; ++ni)
                acc[mi][ni] = SWAP
                    ? __builtin_amdgcn_mfma_f32_16x16x32_bf16(bfr[ni], af[mi], acc[mi][ni], 0, 0, 0)
                    : __builtin_amdgcn_mfma_f32_16x16x32_bf16(af[mi], bfr[ni], acc[mi][ni], 0, 0, 0);
    }
#undef STAGE6
}

// ---------------------------------------------------------------- QKV GEMM
__global__ __launch_bounds__(256, 2) void gemm_qkv(
    const unsigned short* __restrict__ X,
    const unsigned short* __restrict__ W,
    const float* __restrict__ bias,
    unsigned short* __restrict__ Qb,
    unsigned short* __restrict__ Kb,
    unsigned short* __restrict__ Vt)
{
    __shared__ __align__(16) unsigned short lds[24576];   // 48KB
    const int m0 = blockIdx.y * 256;
    const int n0 = blockIdx.x * 128;

    f32x4 acc[8][4];
    f32x4 z = {0.f, 0.f, 0.f, 0.f};
    #pragma unroll
    for (int mi = 0; mi < 8; ++mi)
        #pragma unroll
        for (int ni = 0; ni < 4; ++ni) acc[mi][ni] = z;

    const int region = n0 >> 10;            // 0=Q 1=K 2=V
    if (region < 2) gemm256_core<true >(X, W, m0, n0, lds, acc);
    else            gemm256_core<false>(X, W, m0, n0, lds, acc);

    const int tid  = threadIdx.x;
    const int lane = tid & 63;
    const int w    = tid >> 6;
    const int wm   = (w >> 1) * 128;
    const int wn   = (w & 1) * 64;
    const int l15  = lane & 15;
    const int quad = lane >> 4;
    const int b_idx = m0 >> 11;
    const int t0 = m0 & 2047;

    if (region == 2) {
        // V: transpose through LDS, store coalesced rows of V^T[d][t]
        hard_barrier();
        #pragma unroll
        for (int hn = 0; hn < 2; ++hn) {
            if ((w & 1) == hn) {
                #pragma unroll
                for (int ni = 0; ni < 4; ++ni) {
                    const int nloc = ni * 16 + l15;
                    const float bv = bias[n0 + hn * 64 + nloc];
                    #pragma unroll
                    for (int mi = 0; mi < 8; ++mi) {
                        uint2 pk;
                        pk.x = (unsigned)f32_to_bf16(acc[mi][ni][0] + bv) |
                               ((unsigned)f32_to_bf16(acc[mi][ni][1] + bv) << 16);
                        pk.y = (unsigned)f32_to_bf16(acc[mi][ni][2] + bv) |
                               ((unsigned)f32_to_bf16(acc[mi][ni][3] + bv) << 16);
                        *(uint2*)(lds + nloc * 264 + wm + mi * 16 + quad * 4) = pk;
                    }
                }
            }
            hard_barrier();
            {
                const int row = tid >> 2, seg = tid & 3;
                const int o   = n0 + hn * 64 + row;
                const int oin = o & 1023;
                const int hh  = oin >> 6, d = oin & 63;
                unsigned short* dst = Vt + ((size_t)((b_idx << 4) + hh) * HD + d) * TT
                                        + t0 + seg * 64;
                const unsigned short* src = lds + row * 264 + seg * 64;
                #pragma unroll
                for (int u = 0; u < 8; ++u)
                    *(uint4*)(dst + u * 8) = *(const uint4*)(src + u * 8);
            }
            hard_barrier();
        }
        return;
    }

    // Q/K swapped epilogue: col(l15) = t, rows = o; 8B stores of 4 d's
    unsigned short* dst0 = region ? Kb : Qb;
    const float scl = region ? 1.0f : QSCALE;
    #pragma unroll
    for (int mi = 0; mi < 8; ++mi) {
        const int gm = m0 + wm + mi * 16 + l15;
        const int t  = gm & 2047;
        #pragma unroll
        for (int ni = 0; ni < 4; ++ni) {
            const int o  = n0 + wn + ni * 16 + quad * 4;
            const float4 bv = *(const float4*)(bias + o);
            const int oin = o & 1023;
            const int hh = oin >> 6, d = oin & 63;
            const int bh = (b_idx << 4) + hh;
            const float v0 = (acc[mi][ni][0] + bv.x) * scl;
            const float v1 = (acc[mi][ni][1] + bv.y) * scl;
            const float v2 = (acc[mi][ni][2] + bv.z) * scl;
            const float v3 = (acc[mi][ni][3] + bv.w) * scl;
            uint2 pk;
            pk.x = (unsigned)f32_to_bf16(v0) | ((unsigned)f32_to_bf16(v1) << 16);
            pk.y = (unsigned)f32_to_bf16(v2) | ((unsigned)f32_to_bf16(v3) << 16);
            *(uint2*)(dst0 + (((size_t)(bh * TT + t)) << 6) + d) = pk;
        }
    }
}

// ---------------------------------------------------------------- attention
// REVERTED to the R5 verified structure (74us, clean counters): triple-
// buffered K/V via glds + counted vmcnt, P through LDS (single per-wave
// buffer), f1 then f0 halves with V frags cached in regs. R6/R7's
// in-register bpermute exchange is abandoned (uncontrollable scratch alloca:
// 1GB/dispatch traffic, VGPR 108->84). Single new change this round:
// T5 s_setprio(1) around the QK^T and PV MFMA clusters (m191-verified on
// attn-like independent-block kernels; null only in barrier-lockstep GEMM).
__global__ __launch_bounds__(256, 2) void attn_kernel(
    const unsigned short* __restrict__ Qb,
    const unsigned short* __restrict__ Kb,
    const unsigned short* __restrict__ Vt,
    unsigned short* __restrict__ CTX)
{
    __shared__ __align__(16) unsigned short Kl[3][4096];   // 24KB
    __shared__ __align__(16) unsigned short Vl[3][4096];   // 24KB
    __shared__ __align__(16) unsigned short Pl[4][16 * PPAD]; // 9.2KB

    const int id = blockIdx.x;
    const int qt = 15 - (id >> 6);         // heavy-first
    const int bh = id & 63;
    const int b  = bh >> 4, h = bh & 15;
    const int tid  = threadIdx.x;
    const int lane = tid & 63;
    const int w    = tid >> 6;
    const int l15  = lane & 15;
    const int quad = lane >> 4;
    const int sw   = l15 & 7;              // read-side swizzle key
    const int bhh  = b * NH + h;

    const unsigned short* Kbase = Kb + (size_t)bhh * TT * HD;  // [t][d]
    const unsigned short* Vbase = Vt + (size_t)bhh * HD * TT;  // [d][t]
    const f32x4 z = {0.f, 0.f, 0.f, 0.f};

    const int c1 = tid, c2 = tid + 256;
    const int row1 = c1 >> 3, col1 = ((c1 & 7) ^ (row1 & 7)) * 8;
    const int row2 = c2 >> 3, col2 = ((c2 & 7) ^ (row2 & 7)) * 8;
    unsigned short* dK1 = &Kl[0][(c1 & ~63) * 8];
    unsigned short* dK2 = &Kl[0][(c2 & ~63) * 8];
    unsigned short* dV1 = &Vl[0][(c1 & ~63) * 8];
    unsigned short* dV2 = &Vl[0][(c2 & ~63) * 8];

    const int len = 2 * qt + 2;            // tiles 0..len-1
    const int qb0 = qt * 128;

    const unsigned short* kp1 = Kbase + (size_t)row1 * HD + col1;
    const unsigned short* kp2 = Kbase + (size_t)row2 * HD + col2;
    const unsigned short* vp1 = Vbase + (size_t)row1 * TT + col1;
    const unsigned short* vp2 = Vbase + (size_t)row2 * TT + col2;

    bf16x8 qf[2][2];
    #pragma unroll
    for (int f = 0; f < 2; ++f) {
        const unsigned short* qr =
            Qb + (size_t)(bhh * TT + qb0 + f * 64 + w * 16 + l15) * HD + quad * 8;
        qf[f][0] = *(const bf16x8*)(qr);
        qf[f][1] = *(const bf16x8*)(qr + 32);
    }

    f32x4 o_acc[2][4];
    #pragma unroll
    for (int f = 0; f < 2; ++f)
        #pragma unroll
        for (int di = 0; di < 4; ++di) o_acc[f][di] = z;
    float lrun[2] = {0.f, 0.f};

    // prologue: stage tiles 0,1,(2)
#define STAGE_KV(bufidx)                                               \
    {                                                                  \
        const int nx = (bufidx) * 4096;                                \
        glds16(kp1, dK1 + nx); glds16(kp2, dK2 + nx);                  \
        glds16(vp1, dV1 + nx); glds16(vp2, dV2 + nx);                  \
        kp1 += 64 * HD; kp2 += 64 * HD; vp1 += 64; vp2 += 64;          \
    }
    STAGE_KV(0);
    STAGE_KV(1);
    if (len > 2) STAGE_KV(2);

    for (int i = 0; i < len; ++i) {
        const int cur = i % 3;
        if (i > 0) {
            asm volatile("s_waitcnt lgkmcnt(0)" ::: "memory"); // my reads of retiring buf done
            __builtin_amdgcn_s_barrier();                      // all waves done -> WAR safe
            asm volatile("" ::: "memory");
            if (i + 2 < len) STAGE_KV((i + 2) % 3);
        }
        // retire exactly tile i's 4 loads; keep i+1/i+2 in flight
        if (i + 2 < len)      asm volatile("s_waitcnt vmcnt(8)" ::: "memory");
        else if (i + 1 < len) asm volatile("s_waitcnt vmcnt(4)" ::: "memory");
        else                  asm volatile("s_waitcnt vmcnt(0)" ::: "memory");
        __builtin_amdgcn_s_barrier();                          // tile i visible to all
        asm volatile("" ::: "memory");

        const unsigned short* Kt    = &Kl[0][0] + cur * 4096;
        const unsigned short* Vtile = &Vl[0][0] + cur * 4096;
        const bool f0act = (i < len - 1);

        f32x4 s0[4], s1[4];
        __builtin_amdgcn_s_setprio(1);
        #pragma unroll
        for (int ni = 0; ni < 4; ++ni) {
            const unsigned short* kr = Kt + (ni * 16 + l15) * 64;
            bf16x8 kf0 = *(const bf16x8*)(kr + ((quad ^ sw) * 8));
            bf16x8 kf1 = *(const bf16x8*)(kr + (((quad + 4) ^ sw) * 8));
            if (f0act) {
                f32x4 a = __builtin_amdgcn_mfma_f32_16x16x32_bf16(kf0, qf[0][0], z, 0, 0, 0);
                s0[ni] = __builtin_amdgcn_mfma_f32_16x16x32_bf16(kf1, qf[0][1], a, 0, 0, 0);
            }
            f32x4 a1 = __builtin_amdgcn_mfma_f32_16x16x32_bf16(kf0, qf[1][0], z, 0, 0, 0);
            s1[ni] = __builtin_amdgcn_mfma_f32_16x16x32_bf16(kf1, qf[1][1], a1, 0, 0, 0);
        }
        __builtin_amdgcn_s_setprio(0);

        const int qloc = w * 16 + l15;
        if (f0act && i == len - 2) {
            #pragma unroll
            for (int ni = 0; ni < 4; ++ni)
                #pragma unroll
                for (int r = 0; r < 4; ++r)
                    if (ni * 16 + quad * 4 + r > qloc) s0[ni][r] = -1e30f;
        }
        if (i == len - 1) {
            #pragma unroll
            for (int ni = 0; ni < 4; ++ni)
                #pragma unroll
                for (int r = 0; r < 4; ++r)
                    if (ni * 16 + quad * 4 + r > qloc) s1[ni][r] = -1e30f;
        }

        // tree-reduced sum; P -> single per-wave buffer Pl[w]
        #define SOFTMAX_P(S, F)                                              \
        {                                                                    \
            float tni[4];                                                    \
            _Pragma("unroll")                                                \
            for (int ni = 0; ni < 4; ++ni) {                                 \
                float p0 = __builtin_amdgcn_exp2f(S[ni][0]);                 \
                float p1 = __builtin_amdgcn_exp2f(S[ni][1]);                 \
                float p2 = __builtin_amdgcn_exp2f(S[ni][2]);                 \
                float p3 = __builtin_amdgcn_exp2f(S[ni][3]);                 \
                S[ni][0] = p0; S[ni][1] = p1; S[ni][2] = p2; S[ni][3] = p3;  \
                tni[ni] = (p0 + p1) + (p2 + p3);                             \
            }                                                                \
            lrun[F] += (tni[0] + tni[1]) + (tni[2] + tni[3]);                \
            unsigned short* pwf = Pl[w];                                     \
            _Pragma("unroll")                                                \
            for (int ni = 0; ni < 4; ++ni) {                                 \
                uint2 pk;                                                    \
                pk.x = pack_bf16_trunc(S[ni][0], S[ni][1]);                  \
                pk.y = pack_bf16_trunc(S[ni][2], S[ni][3]);                  \
                *(uint2*)(pwf + l15 * PPAD + ni * 16 + quad * 4) = pk;       \
            }                                                                \
        }

        bf16x8 vf[2][4];
        // f1 half (always active): softmax -> P buffer -> PV, cache V frags
        SOFTMAX_P(s1, 1);
        asm volatile("s_waitcnt lgkmcnt(0)" ::: "memory");  // P RAW (same wave)
        __builtin_amdgcn_s_setprio(1);
        #pragma unroll
        for (int c = 0; c < 2; ++c) {
            bf16x8 pf1 = *(const bf16x8*)(Pl[w] + l15 * PPAD + c * 32 + quad * 8);
            #pragma unroll
            for (int di = 0; di < 4; ++di) {
                vf[c][di] = *(const bf16x8*)(Vtile + (di * 16 + l15) * 64
                                           + (((c * 4 + quad) ^ sw) * 8));
                o_acc[1][di] = __builtin_amdgcn_mfma_f32_16x16x32_bf16(vf[c][di], pf1, o_acc[1][di], 0, 0, 0);
            }
        }
        __builtin_amdgcn_s_setprio(0);
        // f0 half: reuse V regs
        if (f0act) {
            SOFTMAX_P(s0, 0);
            asm volatile("s_waitcnt lgkmcnt(0)" ::: "memory");
            __builtin_amdgcn_s_setprio(1);
            #pragma unroll
            for (int c = 0; c < 2; ++c) {
                bf16x8 pf0 = *(const bf16x8*)(Pl[w] + l15 * PPAD + c * 32 + quad * 8);
                #pragma unroll
                for (int di = 0; di < 4; ++di)
                    o_acc[0][di] = __builtin_amdgcn_mfma_f32_16x16x32_bf16(vf[c][di], pf0, o_acc[0][di], 0, 0, 0);
            }
            __builtin_amdgcn_s_setprio(0);
        }
        #undef SOFTMAX_P
    }
#undef STAGE_KV

    #pragma unroll
    for (int f = 0; f < 2; ++f) {
        float lt = lrun[f];
        lt += __shfl_xor(lt, 16);
        lt += __shfl_xor(lt, 32);
        const float inv = 1.0f / lt;
        unsigned short* crow =
            CTX + (size_t)(b * TT + qb0 + f * 64 + w * 16 + l15) * CM + h * HD;
        #pragma unroll
        for (int di = 0; di < 4; ++di) {
            uint2 pk;
            pk.x = (unsigned)f32_to_bf16(o_acc[f][di][0] * inv) |
                   ((unsigned)f32_to_bf16(o_acc[f][di][1] * inv) << 16);
            pk.y = (unsigned)f32_to_bf16(o_acc[f][di][2] * inv) |
                   ((unsigned)f32_to_bf16(o_acc[f][di][3] * inv) << 16);
            *(uint2*)(crow + di * 16 + quad * 4) = pk;
        }
    }
}

// ---------------------------------------------------------------- out proj
__global__ __launch_bounds__(256, 2) void gemm_out(
    const unsigned short* __restrict__ CTX,
    const unsigned short* __restrict__ W,
    const float* __restrict__ bias,
    float* __restrict__ out)
{
    __shared__ __align__(16) unsigned short lds[24576];
    const int m0 = blockIdx.y * 256;
    const int n0 = blockIdx.x * 128;

    f32x4 acc[8][4];
    f32x4 z = {0.f, 0.f, 0.f, 0.f};
    #pragma unroll
    for (int mi = 0; mi < 8; ++mi)
        #pragma unroll
        for (int ni = 0; ni < 4; ++ni) acc[mi][ni] = z;

    gemm256_core<true>(CTX, W, m0, n0, lds, acc);

    const int tid  = threadIdx.x;
    const int lane = tid & 63;
    const int w    = tid >> 6;
    const int wm   = (w >> 1) * 128;
    const int wn   = (w & 1) * 64;
    const int l15  = lane & 15;
    const int quad = lane >> 4;

    #pragma unroll
    for (int mi = 0; mi < 8; ++mi) {
        const int gm = m0 + wm + mi * 16 + l15;
        float* orow = out + (size_t)gm * CM;
        #pragma unroll
        for (int ni = 0; ni < 4; ++ni) {
            const int o = n0 + wn + ni * 16 + quad * 4;
            const float4 bv = *(const float4*)(bias + o);
            float4 v;
            v.x = acc[mi][ni][0] + bv.x;
            v.y = acc[mi][ni][1] + bv.y;
            v.z = acc[mi][ni][2] + bv.z;
            v.w = acc[mi][ni][3] + bv.w;
            *(float4*)(orow + o) = v;
        }
    }
}

// ---------------------------------------------------------------- launch
extern "C" void kernel_launch(void* const* d_in, const int* in_sizes, int n_in,
                              void* d_out, int out_size, void* d_ws, size_t ws_size,
                              hipStream_t stream) {
    const float* x     = (const float*)d_in[0];
    const float* qkv_w = (const float*)d_in[1];
    const float* qkv_b = (const float*)d_in[2];
    const float* out_w = (const float*)d_in[3];
    const float* out_b = (const float*)d_in[4];
    float* out = (float*)d_out;

    char* ws = (char*)d_ws;
    unsigned short* X16 = (unsigned short*)(ws + 0);         // 16 MB
    unsigned short* W1  = (unsigned short*)(ws + 16777216);  // 6 MB
    unsigned short* W2  = (unsigned short*)(ws + 23068672);  // 2 MB
    unsigned short* Qb  = (unsigned short*)(ws + 25165824);  // 16 MB
    unsigned short* Kb  = (unsigned short*)(ws + 41943040);  // 16 MB
    unsigned short* Vt  = (unsigned short*)(ws + 58720256);  // 16 MB
    unsigned short* CTX = (unsigned short*)(ws + 75497472);  // 16 MB  (~92 MB)

    cast_all<<<12288, 256, 0, stream>>>(x, qkv_w, out_w, X16, W1, W2);

    gemm_qkv<<<dim3(24, 32), 256, 0, stream>>>(X16, W1, qkv_b, Qb, Kb, Vt);
    attn_kernel<<<1024, 256, 0, stream>>>(Qb, Kb, Vt, CTX);
    gemm_out<<<dim3(8, 32), 256, 0, stream>>>(CTX, W2, out_b, out);
}